// Round 15
// baseline (436.993 us; speedup 1.0000x reference)
//
#include <hip/hip_runtime.h>
#include <hip/hip_bf16.h>

typedef short bf16x8 __attribute__((ext_vector_type(8)));
typedef float f32x4  __attribute__((ext_vector_type(4)));

#define NB 64
#define NN 512
#define DD 128
#define PREPS 6

// RNE float -> bf16 (finite inputs)
__device__ __forceinline__ unsigned short f2bf(float f) {
    unsigned int u = __float_as_uint(f);
    unsigned int r = (u + 0x7FFFu + ((u >> 16) & 1u)) >> 16;
    return (unsigned short)r;
}

// ---------- P0: fill clone. Natural block order, grid-stride, 1KB/instr ----
__global__ __launch_bounds__(256) void ASG_p0_fill(float* __restrict__ out)
{
    f32x4* o4 = reinterpret_cast<f32x4*>(out);
    float v = 0.5f;
    asm volatile("" : "+v"(v));
    const f32x4 val = (f32x4){v, v, v, v};
#pragma unroll 1
    for (int rep = 0; rep < PREPS; ++rep) {
        f32x4* o = o4;
        asm volatile("" : "+v"(o));
        size_t idx = (size_t)blockIdx.x * 256 + threadIdx.x;
#pragma unroll 1
        for (int it = 0; it < 16; ++it, idx += 524288)
            o[idx] = val;
    }
}

// ---------- P1: P0 + XCD-pinned contiguous regions -------------------------
__global__ __launch_bounds__(256) void ASG_p1_pinned(float* __restrict__ out)
{
    f32x4* o4 = reinterpret_cast<f32x4*>(out);
    float v = 0.5f;
    asm volatile("" : "+v"(v));
    const f32x4 val = (f32x4){v, v, v, v};
    const int xcd = blockIdx.x & 7;
    const int q   = blockIdx.x >> 3;           // 0..255
    const size_t region = (size_t)xcd * 1048576;   // f32x4 units (16.8MB/XCD)
#pragma unroll 1
    for (int rep = 0; rep < PREPS; ++rep) {
        f32x4* o = o4;
        asm volatile("" : "+v"(o));
        size_t idx = region + (size_t)q * 256 + threadIdx.x;
#pragma unroll 1
        for (int it = 0; it < 16; ++it, idx += 65536)
            o[idx] = val;
    }
}

// ---------- P2/P3: R8's exact store addressing; P3 adds LDS round-trip -----
template <int WITH_LDS>
__global__ __launch_bounds__(256, 4) void ASG_p23_shape(float* __restrict__ out)
{
    const int id  = blockIdx.x;
    const int xcd = id & 7;
    const int q   = id >> 3;
    const int b   = xcd + 8 * (q >> 5);
    const int t   = q & 31;
    const int bi  = t >> 3;
    const int bj  = t & 7;

    const int tid = threadIdx.x;
    const int wid = tid >> 6, lane = tid & 63;
    const int wr  = wid >> 1, wc = wid & 1;
    const int row0 = bi * 128 + wr * 64;
    const int col0 = bj * 64  + wc * 32;
    const int lo = lane & 15, hi = lane >> 4;

    __shared__ float xpose[4][16 * 36];
    float* xp = xpose[wid];
    // force LDS allocation in both variants (equal occupancy)
    xp[tid & 63] = 0.0f;

    float v = 0.5f;
    asm volatile("" : "+v"(v));
    const int c4 = (lane & 7) * 4;
    const int jbase = col0 + c4;

    float* oA_base = out + (size_t)b * NN * NN;
    float* oS_base = out + (size_t)NB * NN * NN + (size_t)b * NN * NN;

#pragma unroll 1
    for (int rep = 0; rep < PREPS; ++rep) {
        float* outA = oA_base;
        float* outS = oS_base;
        asm volatile("" : "+v"(outA), "+v"(outS), "+v"(v));
        const f32x4 val = (f32x4){v, v, v, v};
#pragma unroll
        for (int m = 0; m < 4; ++m) {
            if constexpr (WITH_LDS) {
#pragma unroll
                for (int n = 0; n < 2; ++n)
#pragma unroll
                    for (int r = 0; r < 4; ++r)
                        xp[(hi * 4 + r) * 36 + n * 16 + lo] = v + r;
            }
#pragma unroll
            for (int p2 = 0; p2 < 2; ++p2) {
                const int rr = p2 * 8 + (lane >> 3);
                f32x4 cv;
                if constexpr (WITH_LDS)
                    cv = *reinterpret_cast<const f32x4*>(&xp[rr * 36 + c4]);
                else
                    cv = val;
                const int i = row0 + m * 16 + rr;
                const size_t off = (size_t)i * NN + jbase;
                *reinterpret_cast<f32x4*>(outA + off) = cv;
                *reinterpret_cast<f32x4*>(outS + off) = cv;
            }
        }
    }
}

// ---------- production (R8 champion, unchanged) -----------------------------
__global__ __launch_bounds__(256) void ASG_norm_kernel(
    const float* __restrict__ fea, unsigned int* __restrict__ fn)
{
    const int id   = blockIdx.x;
    const int xcd  = id & 7;
    const int q    = id >> 3;
    const int b    = xcd + 8 * (q >> 5);
    const int t    = q & 31;
    const int wid  = threadIdx.x >> 6;
    const int lane = threadIdx.x & 63;
    const int row0 = b * NN + t * 16 + wid * 4;
    const float2* src = reinterpret_cast<const float2*>(fea);

    float2 v[4];
    float  s[4];
#pragma unroll
    for (int rr = 0; rr < 4; ++rr) {
        v[rr] = src[(size_t)(row0 + rr) * (DD / 2) + lane];
        s[rr] = v[rr].x * v[rr].x + v[rr].y * v[rr].y;
    }
#pragma unroll
    for (int o = 32; o; o >>= 1) {
#pragma unroll
        for (int rr = 0; rr < 4; ++rr) s[rr] += __shfl_xor(s[rr], o);
    }
#pragma unroll
    for (int rr = 0; rr < 4; ++rr) {
        const float scale = 1.0f / fmaxf(sqrtf(s[rr]), 1e-8f);
        const unsigned short a = f2bf(v[rr].x * scale);
        const unsigned short bb = f2bf(v[rr].y * scale);
        fn[(size_t)(row0 + rr) * (DD / 2) + lane] =
            (unsigned int)a | ((unsigned int)bb << 16);
    }
}

__global__ __launch_bounds__(256, 4) void ASG_adj_kernel(
    const unsigned short* __restrict__ fn, const float* __restrict__ coord,
    float* __restrict__ out)
{
    const int id  = blockIdx.x;
    const int xcd = id & 7;
    const int q   = id >> 3;
    const int b   = xcd + 8 * (q >> 5);
    const int t   = q & 31;
    const int bi  = t >> 3;
    const int bj  = t & 7;

    const int tid = threadIdx.x;
    const int wid = tid >> 6, lane = tid & 63;
    const int wr  = wid >> 1, wc = wid & 1;
    const int row0 = bi * 128 + wr * 64;
    const int col0 = bj * 64  + wc * 32;
    const int lo = lane & 15, hi = lane >> 4;

    __shared__ float2 crow[128];
    __shared__ float2 ccol[64];
    __shared__ float  xpose[4][16 * 36];

    const float2* cb = reinterpret_cast<const float2*>(coord) + (size_t)b * NN;
    if (tid < 128)      crow[tid] = cb[bi * 128 + tid];
    else if (tid < 192) ccol[tid - 128] = cb[bj * 64 + (tid - 128)];
    __syncthreads();

    const unsigned short* fb = fn + (size_t)b * NN * DD;
    const int lk = hi * 8;

    bf16x8 bfrag[2][4];
#pragma unroll
    for (int n = 0; n < 2; ++n) {
        const unsigned short* p = fb + (size_t)(col0 + n * 16 + lo) * DD + lk;
#pragma unroll
        for (int kk = 0; kk < 4; ++kk)
            bfrag[n][kk] = *reinterpret_cast<const bf16x8*>(p + kk * 32);
    }

    float* outA = out + (size_t)b * NN * NN;
    float* outS = out + (size_t)NB * NN * NN + (size_t)b * NN * NN;
    float* xp = xpose[wid];

    const int c4 = (lane & 7) * 4;
    const int jbase = col0 + c4;
    float2 cj[4];
#pragma unroll
    for (int q2 = 0; q2 < 4; ++q2) cj[q2] = ccol[wc * 32 + c4 + q2];

#define LOADA(DST, MM)                                                        \
    {                                                                         \
        const unsigned short* p =                                             \
            fb + (size_t)(row0 + (MM) * 16 + lo) * DD + lk;                   \
        _Pragma("unroll")                                                     \
        for (int kk = 0; kk < 4; ++kk)                                        \
            DST[kk] = *reinterpret_cast<const bf16x8*>(p + kk * 32);          \
    }

#define STEP(MM, CURF, NEXTF, DO_PREF)                                        \
    {                                                                         \
        if (DO_PREF) LOADA(NEXTF, (MM) + 1);                                  \
        f32x4 acc[2];                                                         \
        _Pragma("unroll")                                                     \
        for (int n = 0; n < 2; ++n) acc[n] = (f32x4){0.f, 0.f, 0.f, 0.f};     \
        _Pragma("unroll")                                                     \
        for (int n = 0; n < 2; ++n)                                           \
            _Pragma("unroll")                                                 \
            for (int kk = 0; kk < 4; ++kk)                                    \
                acc[n] = __builtin_amdgcn_mfma_f32_16x16x32_bf16(             \
                    CURF[kk], bfrag[n][kk], acc[n], 0, 0, 0);                 \
        _Pragma("unroll")                                                     \
        for (int n = 0; n < 2; ++n)                                           \
            _Pragma("unroll")                                                 \
            for (int r = 0; r < 4; ++r)                                       \
                xp[(hi * 4 + r) * 36 + n * 16 + lo] = acc[n][r];              \
        _Pragma("unroll")                                                     \
        for (int p2 = 0; p2 < 2; ++p2) {                                      \
            const int rr = p2 * 8 + (lane >> 3);                              \
            const f32x4 cv =                                                  \
                *reinterpret_cast<const f32x4*>(&xp[rr * 36 + c4]);           \
            const int i = row0 + (MM) * 16 + rr;                              \
            const float2 ci = crow[wr * 64 + (MM) * 16 + rr];                 \
            f32x4 av, sv;                                                     \
            _Pragma("unroll")                                                 \
            for (int q2 = 0; q2 < 4; ++q2) {                                  \
                const int j = jbase + q2;                                     \
                const float dx = ci.x - cj[q2].x;                             \
                const float dy = ci.y - cj[q2].y;                             \
                const float d2 =                                              \
                    __fadd_rn(__fmul_rn(dx, dx), __fmul_rn(dy, dy));          \
                const float dist = __fsqrt_rn(d2);                            \
                const bool diag = (i == j);                                   \
                av[q2] = diag ? 0.0f : cv[q2] * __expf(-dist);                \
                sv[q2] = (!diag && dist < 1.0f) ? 1.0f : 0.0f;                \
            }                                                                 \
            const size_t off = (size_t)i * NN + jbase;                        \
            *reinterpret_cast<f32x4*>(outA + off) = av;                       \
            *reinterpret_cast<f32x4*>(outS + off) = sv;                       \
        }                                                                     \
    }

    bf16x8 af0[4], af1[4];
    LOADA(af0, 0);
    STEP(0, af0, af1, 1);
    STEP(1, af1, af0, 1);
    STEP(2, af0, af1, 1);
    STEP(3, af1, af0, 0);

#undef STEP
#undef LOADA
}

extern "C" void kernel_launch(void* const* d_in, const int* in_sizes, int n_in,
                              void* d_out, int out_size, void* d_ws, size_t ws_size,
                              hipStream_t stream) {
    const float* fea   = (const float*)d_in[0];   // [64,512,128] f32
    const float* coord = (const float*)d_in[1];   // [64,512,2]   f32
    float* out = (float*)d_out;                   // [2,64,512,512] f32
    unsigned int* fn_ws = (unsigned int*)d_ws;    // bf16 fn, 8 MB

    // ---- store-pattern probe matrix (sacrificial; output overwritten) ----
    ASG_p0_fill<<<dim3(2048), 256, 0, stream>>>(out);          // fill clone
    ASG_p1_pinned<<<dim3(2048), 256, 0, stream>>>(out);        // + pinning
    ASG_p23_shape<0><<<dim3(2048), 256, 0, stream>>>(out);     // R8 shape
    ASG_p23_shape<1><<<dim3(2048), 256, 0, stream>>>(out);     // + LDS dep

    // ---- production pair LAST -> correct output ----
    ASG_norm_kernel<<<dim3(2048), 256, 0, stream>>>(fea, fn_ws);
    ASG_adj_kernel<<<dim3(2048), 256, 0, stream>>>(
        (const unsigned short*)fn_ws, coord, out);
}

// Round 16
// 43.367 us; speedup vs baseline: 10.0767x; 10.0767x over previous
//
#include <hip/hip_runtime.h>
#include <hip/hip_bf16.h>

typedef short bf16x8 __attribute__((ext_vector_type(8)));
typedef float f32x4  __attribute__((ext_vector_type(4)));

#define NB 64
#define NN 512
#define DD 128

// RNE float -> bf16 (finite inputs)
__device__ __forceinline__ unsigned short f2bf(float f) {
    unsigned int u = __float_as_uint(f);
    unsigned int r = (u + 0x7FFFu + ((u >> 16) & 1u)) >> 16;
    return (unsigned short)r;
}

// Kernel 1: per-row L2 normalize, write bf16 fn into workspace (XCD-pinned).
__global__ __launch_bounds__(256) void ASG_norm_kernel(
    const float* __restrict__ fea, unsigned int* __restrict__ fn)
{
    const int id   = blockIdx.x;
    const int xcd  = id & 7;
    const int q    = id >> 3;
    const int b    = xcd + 8 * (q >> 5);
    const int t    = q & 31;
    const int wid  = threadIdx.x >> 6;
    const int lane = threadIdx.x & 63;
    const int row0 = b * NN + t * 16 + wid * 4;
    const float2* src = reinterpret_cast<const float2*>(fea);

    float2 v[4];
    float  s[4];
#pragma unroll
    for (int rr = 0; rr < 4; ++rr) {
        v[rr] = src[(size_t)(row0 + rr) * (DD / 2) + lane];
        s[rr] = v[rr].x * v[rr].x + v[rr].y * v[rr].y;
    }
#pragma unroll
    for (int o = 32; o; o >>= 1) {
#pragma unroll
        for (int rr = 0; rr < 4; ++rr) s[rr] += __shfl_xor(s[rr], o);
    }
#pragma unroll
    for (int rr = 0; rr < 4; ++rr) {
        const float scale = 1.0f / fmaxf(sqrtf(s[rr]), 1e-8f);
        const unsigned short a = f2bf(v[rr].x * scale);
        const unsigned short bb = f2bf(v[rr].y * scale);
        fn[(size_t)(row0 + rr) * (DD / 2) + lane] =
            (unsigned int)a | ((unsigned int)bb << 16);
    }
}

// Kernel 2: R8 MFMA core, but stores DECOUPLED from the compute chain:
// C-phase writes finished av into LDS (nothing depends on the write);
// after a barrier, S-phase issues pure streaming stores (P3-proven fast
// pattern) while the next C-phase's MFMAs run behind them. sv is
// recomputed in S-phase (shallow chain, no MFMA dep). 2-stage pipeline.
__global__ __launch_bounds__(256, 4) void ASG_adj_kernel(
    const unsigned short* __restrict__ fn, const float* __restrict__ coord,
    float* __restrict__ out)
{
    const int id  = blockIdx.x;        // 0..2047
    const int xcd = id & 7;
    const int q   = id >> 3;           // 0..255
    const int b   = xcd + 8 * (q >> 5);
    const int t   = q & 31;
    const int bi  = t >> 3;            // 128-row stripe 0..3
    const int bj  = t & 7;             // 64-col stripe 0..7

    const int tid = threadIdx.x;
    const int wid = tid >> 6, lane = tid & 63;
    const int wr  = wid >> 1, wc = wid & 1;
    const int row0 = bi * 128 + wr * 64;
    const int col0 = bj * 64  + wc * 32;
    const int lo = lane & 15, hi = lane >> 4;

    __shared__ float2 crow[128];
    __shared__ float2 ccol[64];
    __shared__ float  av_lds[128 * 68];   // staged async plane (pad 68)

    const float2* cb = reinterpret_cast<const float2*>(coord) + (size_t)b * NN;
    if (tid < 128)      crow[tid] = cb[bi * 128 + tid];
    else if (tid < 192) ccol[tid - 128] = cb[bj * 64 + (tid - 128)];
    __syncthreads();

    const unsigned short* fb = fn + (size_t)b * NN * DD;
    const int lk = hi * 8;             // k start (bf16 elements)

    bf16x8 bfrag[2][4];
#pragma unroll
    for (int n = 0; n < 2; ++n) {
        const unsigned short* p = fb + (size_t)(col0 + n * 16 + lo) * DD + lk;
#pragma unroll
        for (int kk = 0; kk < 4; ++kk)
            bfrag[n][kk] = *reinterpret_cast<const bf16x8*>(p + kk * 32);
    }

    float* outA = out + (size_t)b * NN * NN;
    float* outS = out + (size_t)NB * NN * NN + (size_t)b * NN * NN;

// ---- C(m): MFMA + av epilogue -> LDS only (no global stores) ----
#define LOADA(DST, MM)                                                        \
    {                                                                         \
        const unsigned short* p =                                             \
            fb + (size_t)(row0 + (MM) * 16 + lo) * DD + lk;                   \
        _Pragma("unroll")                                                     \
        for (int kk = 0; kk < 4; ++kk)                                        \
            DST[kk] = *reinterpret_cast<const bf16x8*>(p + kk * 32);          \
    }

#define CSTEP(MM, CURF, NEXTF, DO_PREF)                                       \
    {                                                                         \
        if (DO_PREF) LOADA(NEXTF, (MM) + 1);                                  \
        f32x4 acc[2];                                                         \
        _Pragma("unroll")                                                     \
        for (int n = 0; n < 2; ++n) acc[n] = (f32x4){0.f, 0.f, 0.f, 0.f};     \
        _Pragma("unroll")                                                     \
        for (int n = 0; n < 2; ++n)                                           \
            _Pragma("unroll")                                                 \
            for (int kk = 0; kk < 4; ++kk)                                    \
                acc[n] = __builtin_amdgcn_mfma_f32_16x16x32_bf16(             \
                    CURF[kk], bfrag[n][kk], acc[n], 0, 0, 0);                 \
        _Pragma("unroll")                                                     \
        for (int n = 0; n < 2; ++n) {                                         \
            const int lc = wc * 32 + n * 16 + lo;                             \
            const int j  = bj * 64 + lc;                                      \
            const float2 cj = ccol[lc];                                       \
            _Pragma("unroll")                                                 \
            for (int r = 0; r < 4; ++r) {                                     \
                const int lr = wr * 64 + (MM) * 16 + hi * 4 + r;              \
                const int i  = bi * 128 + lr;                                 \
                const float2 ci = crow[lr];                                   \
                /* bit-exact numpy chain: mul, mul, add, sqrt (no FMA) */     \
                const float dx = ci.x - cj.x;                                 \
                const float dy = ci.y - cj.y;                                 \
                const float d2 =                                              \
                    __fadd_rn(__fmul_rn(dx, dx), __fmul_rn(dy, dy));          \
                const float dist = __fsqrt_rn(d2);                            \
                const bool diag = (i == j);                                   \
                av_lds[lr * 68 + lc] =                                        \
                    diag ? 0.0f : acc[n][r] * __expf(-dist);                  \
            }                                                                 \
        }                                                                     \
    }

// ---- S(h): pure streaming stores of settled rows; sv recomputed ----
    const int r4  = lane >> 4;         // 0..3
    const int c4l = (lane & 15) * 4;   // col within 64
    float2 cj2[4];
#pragma unroll
    for (int c = 0; c < 4; ++c) cj2[c] = ccol[c4l + c];
    const int lrb0 = (wid & 1) * 64 + (wid >> 1) * 16;

#define SSTEP(H)                                                              \
    {                                                                         \
        _Pragma("unroll")                                                     \
        for (int p = 0; p < 4; ++p) {                                         \
            const int lr = lrb0 + (H) * 32 + p * 4 + r4;                      \
            const int gi = bi * 128 + lr;                                     \
            const f32x4 av4 =                                                 \
                *reinterpret_cast<const f32x4*>(&av_lds[lr * 68 + c4l]);      \
            const size_t off = (size_t)gi * NN + bj * 64 + c4l;               \
            *reinterpret_cast<f32x4*>(outA + off) = av4;                      \
            const float2 ci = crow[lr];                                       \
            f32x4 sv;                                                         \
            _Pragma("unroll")                                                 \
            for (int c = 0; c < 4; ++c) {                                     \
                const float dx = ci.x - cj2[c].x;                             \
                const float dy = ci.y - cj2[c].y;                             \
                const float d2 =                                              \
                    __fadd_rn(__fmul_rn(dx, dx), __fmul_rn(dy, dy));          \
                const float dist = __fsqrt_rn(d2);                            \
                const bool diag = (gi == bj * 64 + c4l + c);                  \
                sv[c] = (!diag && dist < 1.0f) ? 1.0f : 0.0f;                 \
            }                                                                 \
            *reinterpret_cast<f32x4*>(outS + off) = sv;                       \
        }                                                                     \
    }

    bf16x8 af0[4], af1[4];
    LOADA(af0, 0);
    CSTEP(0, af0, af1, 1);
    CSTEP(1, af1, af0, 1);
    __syncthreads();           // rows 0-31 / 64-95 settled
    SSTEP(0);                  // stores fly while C(2,3) computes
    CSTEP(2, af0, af1, 1);
    CSTEP(3, af1, af0, 0);
    __syncthreads();           // rows 32-63 / 96-127 settled
    SSTEP(1);

#undef SSTEP
#undef CSTEP
#undef LOADA
}

extern "C" void kernel_launch(void* const* d_in, const int* in_sizes, int n_in,
                              void* d_out, int out_size, void* d_ws, size_t ws_size,
                              hipStream_t stream) {
    const float* fea   = (const float*)d_in[0];   // [64,512,128] f32
    const float* coord = (const float*)d_in[1];   // [64,512,2]   f32
    float* out = (float*)d_out;                   // [2,64,512,512] f32
    unsigned int* fn_ws = (unsigned int*)d_ws;    // bf16 fn, 8 MB

    ASG_norm_kernel<<<dim3(2048), 256, 0, stream>>>(fea, fn_ws);
    ASG_adj_kernel<<<dim3(2048), 256, 0, stream>>>(
        (const unsigned short*)fn_ws, coord, out);
}